// Round 7
// baseline (18161.688 us; speedup 1.0000x reference)
//
#include <hip/hip_runtime.h>

#define BB 32
#define TT 150
#define LL 400
#define FEATD 512
#define RNND 512
#define ATTD 512
#define EMBD 256
#define VOCABD 5000
#define G3 1536

__device__ __forceinline__ float fsigmoid(float x) { return 1.f / (1.f + __expf(-x)); }
__device__ __forceinline__ float ftanh(float x) {
    x = fminf(15.f, fmaxf(-15.f, x));
    float e = __expf(2.f * x);
    return 1.f - 2.f / (e + 1.f);
}
__device__ __forceinline__ void fma4(float4& a, const float4 w, const float s) {
    a.x += w.x * s; a.y += w.y * s; a.z += w.z * s; a.w += w.w * s;
}

// ---------------- one-time GEMM: [B*L,512] @ [512,512] -> out (fp and G) ----------------
__global__ void __launch_bounds__(256) k_proj512(const float* __restrict__ features,
                                                 const float* __restrict__ W,
                                                 float* __restrict__ outb) {
    __shared__ float sa[64 * 68];
    int blt = blockIdx.x >> 2, at = blockIdx.x & 3;
    int bl0 = blt * 64;
    int tid = threadIdx.x;
    int aq = tid & 31, blg = tid >> 5;
    float4 acc[8] = {};
    for (int kc = 0; kc < FEATD; kc += 64) {
        __syncthreads();
        for (int it = 0; it < 16; ++it) {
            int lin = it * 256 + tid;
            int k = lin & 63, bl = lin >> 6;
            sa[k * 68 + bl] = features[((size_t)bl0 + bl) * FEATD + kc + k];
        }
        __syncthreads();
#pragma unroll 4
        for (int k = 0; k < 64; ++k) {
            float4 w = *(const float4*)&W[(size_t)(kc + k) * 512 + at * 128 + aq * 4];
            float4 s0 = *(const float4*)&sa[k * 68 + blg * 8];
            float4 s1 = *(const float4*)&sa[k * 68 + blg * 8 + 4];
            fma4(acc[0], w, s0.x); fma4(acc[1], w, s0.y);
            fma4(acc[2], w, s0.z); fma4(acc[3], w, s0.w);
            fma4(acc[4], w, s1.x); fma4(acc[5], w, s1.y);
            fma4(acc[6], w, s1.z); fma4(acc[7], w, s1.w);
        }
    }
#pragma unroll
    for (int i = 0; i < 8; ++i)
        *(float4*)&outb[((size_t)bl0 + blg * 8 + i) * 512 + at * 128 + aq * 4] = acc[i];
}

// ---------------- D1: gate GEMM partials. 120 blocks ----------------
// mx: [emb(tok) | lo(t-1)] (K=768) @ Wk -> mxp[3], mh: h(t-1) @ Wr -> mhp[2].
// lo(t-1) read from materialized los slot t (slot 0 = zeros).
__global__ void __launch_bounds__(256) k_gates(
    const float* __restrict__ emb, const int* __restrict__ formula,
    const float* __restrict__ Wk, const float* __restrict__ Wr,
    const float* __restrict__ hin, const float* __restrict__ lo,
    float* __restrict__ mxp, float* __restrict__ mhp, int t) {
    __shared__ float sm[256 * 36];
    __shared__ int stok[BB];
    int id = blockIdx.x, tid = threadIdx.x;
    bool isMX = id < 72;
    int jt, ks; const float* W; float* ob;
    if (isMX) { jt = id / 3; ks = id % 3; W = Wk; ob = mxp; }
    else { int r = id - 72; jt = r >> 1; ks = r & 1; W = Wr; ob = mhp; }
    int k0 = ks * 256;
    if (isMX && ks == 0 && tid < BB) stok[tid] = formula[tid * TT + t];
    __syncthreads();
    for (int it = 0; it < 32; ++it) {
        int lin = it * 256 + tid;
        int k = lin & 255, b = lin >> 8;
        float v;
        if (!isMX) v = hin[(size_t)b * RNND + k0 + k];
        else if (ks == 0) v = emb[(size_t)stok[b] * EMBD + k];
        else v = lo[(size_t)b * RNND + (ks - 1) * 256 + k];
        sm[k * 36 + b] = v;
    }
    __syncthreads();
    int jq = tid & 15, bg = tid >> 4;
    int j = jt * 64 + jq * 4;
    float4 a0 = {0, 0, 0, 0}, a1 = {0, 0, 0, 0};
#pragma unroll 4
    for (int k = 0; k < 256; ++k) {
        float4 w = *(const float4*)&W[(size_t)(k0 + k) * G3 + j];
        float2 s = *(const float2*)&sm[k * 36 + bg * 2];
        fma4(a0, w, s.x);
        fma4(a1, w, s.y);
    }
    int b = bg * 2;
    *(float4*)&ob[((size_t)ks * BB + b) * G3 + j] = a0;
    *(float4*)&ob[((size_t)ks * BB + b + 1) * G3 + j] = a1;
}

// ---------------- D2: combine -> h(t); q-slice; hpart-slice; partial scores ----------------
// 256 blocks = b(32) x as(8). Each block: full GRU combine for b (redundant x8, cheap),
// q[b, as*64..+64] and hpart[b, as*64..+64] via 4-way split-k, then
// psc[as,b,l] = sum_{a in slice} tanh(fp[b,l,a]+q[a])*V[a] for all 400 l.
__global__ void __launch_bounds__(256) k_combine(
    const float* __restrict__ mxp, const float* __restrict__ mhp,
    const float* __restrict__ gruB, const float* __restrict__ W2,
    const float* __restrict__ outW, const float* __restrict__ V,
    const float* __restrict__ fp, const float* __restrict__ hin,
    float* __restrict__ hout, float* __restrict__ hpart,
    float* __restrict__ psc) {
    __shared__ float sh[RNND];
    __shared__ float sred[512];
    __shared__ float sq[64];
    __shared__ float sV[64];
    int b = blockIdx.x >> 3, as = blockIdx.x & 7;
    int tid = threadIdx.x;
    size_t m0 = (size_t)(0 * BB + b) * G3, m1 = (size_t)(1 * BB + b) * G3,
           m2 = (size_t)(2 * BB + b) * G3;
#pragma unroll
    for (int jj = 0; jj < 2; ++jj) {
        int j = tid + jj * 256;
        float xz = gruB[j] + mxp[m0 + j] + mxp[m1 + j] + mxp[m2 + j];
        float xr = gruB[512 + j] + mxp[m0 + 512 + j] + mxp[m1 + 512 + j] + mxp[m2 + 512 + j];
        float xh = gruB[1024 + j] + mxp[m0 + 1024 + j] + mxp[m1 + 1024 + j] + mxp[m2 + 1024 + j];
        float rz = gruB[G3 + j] + mhp[m0 + j] + mhp[m1 + j];
        float rr = gruB[G3 + 512 + j] + mhp[m0 + 512 + j] + mhp[m1 + 512 + j];
        float rh = gruB[G3 + 1024 + j] + mhp[m0 + 1024 + j] + mhp[m1 + 1024 + j];
        float z = fsigmoid(xz + rz), r = fsigmoid(xr + rr);
        float hh = ftanh(xh + r * rh);
        float hn = z * hin[(size_t)b * RNND + j] + (1.f - z) * hh;
        sh[j] = hn;
        if (as == 0) hout[(size_t)b * RNND + j] = hn;
    }
    if (tid < 64) sV[tid] = V[as * 64 + tid];
    __syncthreads();

    // q and hpart slices (64 wide), 4-way split-k
    int col = tid & 63, kq = tid >> 6;
    int a = as * 64 + col;
    float aq = 0.f, ah = 0.f;
    int kb = kq * 128;
#pragma unroll 8
    for (int k = 0; k < 128; ++k) {
        float s = sh[kb + k];
        aq += s * W2[(size_t)(kb + k) * ATTD + a];
        ah += s * outW[(size_t)(kb + k) * RNND + a];
    }
    sred[kq * 64 + col] = aq;
    sred[256 + kq * 64 + col] = ah;
    __syncthreads();
    if (tid < 64) {
        sq[tid] = sred[tid] + sred[64 + tid] + sred[128 + tid] + sred[192 + tid];
    } else if (tid < 128) {
        int c = tid - 64;
        hpart[(size_t)b * RNND + as * 64 + c] =
            sred[256 + c] + sred[320 + c] + sred[384 + c] + sred[448 + c];
    }
    __syncthreads();

    // partial scores: wave per l (one a per lane)
    int lane = tid & 63, wv = tid >> 6;
    float qv = sq[lane], vv = sV[lane];
    for (int l = wv; l < LL; l += 4) {
        float d = ftanh(fp[((size_t)b * LL + l) * ATTD + as * 64 + lane] + qv) * vv;
#pragma unroll
        for (int o = 32; o > 0; o >>= 1) d += __shfl_xor(d, o);
        if (lane == 0) psc[((size_t)as * BB + b) * LL + l] = d;
    }
}

// ---------------- D3: exp + sum + outpre + tanh -> lo(t). 128 blocks = b(32) x jq(4) ----------------
// outpre[b,j] = hpart[b,j] + inv * sum_l e_l * G[b,l,j]; lo written to los slot t+1.
__global__ void __launch_bounds__(256) k_outlo(
    const float* __restrict__ psc, const float* __restrict__ G,
    const float* __restrict__ hpart, float* __restrict__ lo_out) {
    __shared__ float se[LL];
    __shared__ float sred[256];
    __shared__ float sinv;
    int b = blockIdx.x >> 2, jq = blockIdx.x & 3;
    int tid = threadIdx.x;
    for (int l = tid; l < LL; l += 256) {
        float s = 0.f;
#pragma unroll
        for (int as = 0; as < 8; ++as) s += psc[((size_t)as * BB + b) * LL + l];
        se[l] = __expf(s);  // |score| <= sum|V| ~ 20, fp32-safe
    }
    __syncthreads();
    float x = se[tid] + ((tid < LL - 256) ? se[tid + 256] : 0.f);
    sred[tid] = x;
    __syncthreads();
#pragma unroll
    for (int s = 128; s > 0; s >>= 1) {
        if (tid < s) sred[tid] += sred[tid + s];
        __syncthreads();
    }
    if (tid == 0) sinv = 1.f / sred[0];
    __syncthreads();

    // outpre slice: 128 j-cols x 2-way split-l
    int jc = tid & 127, lh = tid >> 7;
    int j = jq * 128 + jc;
    float acc = 0.f;
    int l0 = lh * 200;
#pragma unroll 4
    for (int l = 0; l < 200; ++l)
        acc += se[l0 + l] * G[((size_t)b * LL + l0 + l) * RNND + j];
    sred[lh * 128 + jc] = acc;
    __syncthreads();
    if (tid < 128) {
        float op = hpart[(size_t)b * RNND + jq * 128 + tid] +
                   sinv * (sred[tid] + sred[128 + tid]);
        lo_out[(size_t)b * RNND + jq * 128 + tid] = ftanh(op);
    }
}

// ---------------- final: logits = los[1..150] @ projW ----------------
// row r = b*150+t -> los slot t+1. 75 row-tiles x 40 v-tiles.
__global__ void __launch_bounds__(256) k_final(
    const float* __restrict__ los, const float* __restrict__ Wp,
    float* __restrict__ out) {
    __shared__ float sa[64 * 68];
    __shared__ unsigned srow[64];
    int mt = blockIdx.x / 40, vt = blockIdx.x % 40;
    int r0 = mt * 64;
    int tid = threadIdx.x;
    if (tid < 64) {
        int r = r0 + tid;
        int bb = r / TT, t = r % TT;
        srow[tid] = (unsigned)(((size_t)(t + 1) * BB + bb) * RNND);
    }
    int aq = tid & 31, blg = tid >> 5;
    int v = vt * 128 + aq * 4;
    bool vok = v < VOCABD;
    float4 acc[8] = {};
    __syncthreads();
    for (int kc = 0; kc < RNND; kc += 64) {
        for (int it = 0; it < 16; ++it) {
            int lin = it * 256 + tid;
            int k = lin & 63, rl = lin >> 6;
            sa[k * 68 + rl] = los[srow[rl] + kc + k];
        }
        __syncthreads();
        if (vok) {
#pragma unroll 4
            for (int k = 0; k < 64; ++k) {
                float4 w = *(const float4*)&Wp[(size_t)(kc + k) * VOCABD + v];
                float4 s0 = *(const float4*)&sa[k * 68 + blg * 8];
                float4 s1 = *(const float4*)&sa[k * 68 + blg * 8 + 4];
                fma4(acc[0], w, s0.x); fma4(acc[1], w, s0.y);
                fma4(acc[2], w, s0.z); fma4(acc[3], w, s0.w);
                fma4(acc[4], w, s1.x); fma4(acc[5], w, s1.y);
                fma4(acc[6], w, s1.z); fma4(acc[7], w, s1.w);
            }
        }
        __syncthreads();
    }
    if (vok) {
#pragma unroll
        for (int i = 0; i < 8; ++i)
            *(float4*)&out[(size_t)(r0 + blg * 8 + i) * VOCABD + v] = acc[i];
    }
}

extern "C" void kernel_launch(void* const* d_in, const int* in_sizes, int n_in,
                              void* d_out, int out_size, void* d_ws, size_t ws_size,
                              hipStream_t stream) {
    const float* features  = (const float*)d_in[0];
    const float* initstate = (const float*)d_in[1];
    const float* emb       = (const float*)d_in[2];
    const float* gruK      = (const float*)d_in[3];
    const float* gruR      = (const float*)d_in[4];
    const float* gruB      = (const float*)d_in[5];
    const float* W1        = (const float*)d_in[6];
    const float* W2        = (const float*)d_in[7];
    const float* V         = (const float*)d_in[8];
    const float* outW      = (const float*)d_in[9];
    const float* projW     = (const float*)d_in[10];
    const int*   formula   = (const int*)d_in[11];
    float* logits = (float*)d_out;

    float* ws = (float*)d_ws;
    float* h0    = ws;                                  // 16,384
    float* h1    = h0 + (size_t)BB * RNND;              // 16,384
    float* mxp   = h1 + (size_t)BB * RNND;              // 147,456
    float* mhp   = mxp + (size_t)3 * BB * G3;           // 98,304
    float* hpart = mhp + (size_t)2 * BB * G3;           // 16,384
    float* psc   = hpart + (size_t)BB * RNND;           // 102,400
    float* los   = psc + (size_t)8 * BB * LL;           // 151 slots: 2,473,984
    float* fp    = los + (size_t)(TT + 1) * BB * RNND;  // 6,553,600
    float* G     = fp + (size_t)BB * LL * ATTD;         // 6,553,600

    // los slot 0 = lo(-1) = zeros; re-zeroed every call (deterministic).
    hipMemsetAsync(los, 0, (size_t)BB * RNND * sizeof(float), stream);
    hipMemcpyAsync(h0, initstate, (size_t)BB * RNND * sizeof(float),
                   hipMemcpyDeviceToDevice, stream);

    k_proj512<<<800, 256, 0, stream>>>(features, W1, fp);
    k_proj512<<<800, 256, 0, stream>>>(features, outW + (size_t)512 * RNND, G);

    float* hin = h0;
    float* hout = h1;
    for (int t = 0; t < TT; ++t) {
        k_gates<<<120, 256, 0, stream>>>(emb, formula, gruK, gruR, hin,
                                         los + (size_t)t * BB * RNND, mxp, mhp, t);
        k_combine<<<256, 256, 0, stream>>>(mxp, mhp, gruB, W2, outW, V, fp, hin,
                                           hout, hpart, psc);
        k_outlo<<<128, 256, 0, stream>>>(psc, G, hpart,
                                         los + (size_t)(t + 1) * BB * RNND);
        float* tmp = hin; hin = hout; hout = tmp;
    }
    k_final<<<75 * 40, 256, 0, stream>>>(los, projW, logits);
}